// Round 3
// baseline (740.026 us; speedup 1.0000x reference)
//
#include <hip/hip_runtime.h>
#include <math.h>

// MultiHeadAttention_22067541967542 — round 3: MFMA attention + fused rescale.
// B=4, S=1024, D=1024, H=16, dh=64. k/v/is_training dead.
// w_betw == 1/16 exactly (f32 absorption in reference, see round-2 analysis).
// Pipeline:
//   k_bnparams
//   k_gemm<1,relu>: x1 = relu(BN(q)@Wq+bq)            [ws f32, 16MB]
//   k_gemm<0>:      xq = x1@Wqq+bqq                   [d_out out-region]
//   k_cvt:          qhT bf16 [B,H,dh,S]               [ws 0..8MB, aliases dead x1]
//   k_attn_mfma<0>: QK^T (bf16 MFMA) -> sum_l, n_cnt, denom   (stats only)
//   k_wwithin:      f64 z-norm softmax -> w_row = w_within/16/denom
//   k_attn_mfma<1>: recompute QK^T -> p -> attn=p*w_row (write), PV (MFMA),
//                   pv_bf16 = PV*w_row                [ws 8..16MB]
//   k_gemm<3>:      out = pv_bf16 @ Wo + bo
// Precision: bf16 enters only via exp(l) with |l|<~1 (attenuated) and via
// p/pv rounding (~0.2% rel) vs 2% thresholds.

constexpr int Bz = 4, S = 1024, D = 1024, H = 16, DH = 64;
constexpr int N_ROWS = Bz * S; // 4096
#define BN_EPS 1e-3f
#define NEG_BIG -1e9f

typedef __attribute__((ext_vector_type(8))) short bf16x8;
typedef __attribute__((ext_vector_type(8))) unsigned short u16x8;
typedef __attribute__((ext_vector_type(4))) float f32x4;

__device__ inline unsigned short f2bf(float f) {
  union { float f; unsigned int u; } v; v.f = f;
  unsigned int u = v.u;
  return (unsigned short)((u + 0x7FFFu + ((u >> 16) & 1u)) >> 16); // RNE
}
__device__ inline float bf2f(unsigned short h) {
  union { unsigned int u; float f; } v; v.u = ((unsigned int)h) << 16;
  return v.f;
}
__device__ inline bf16x8 pack8(float4 a, float4 b) {
  bf16x8 v;
  v[0] = (short)f2bf(a.x); v[1] = (short)f2bf(a.y);
  v[2] = (short)f2bf(a.z); v[3] = (short)f2bf(a.w);
  v[4] = (short)f2bf(b.x); v[5] = (short)f2bf(b.y);
  v[6] = (short)f2bf(b.z); v[7] = (short)f2bf(b.w);
  return v;
}

__global__ void k_bnparams(const float* __restrict__ gamma, const float* __restrict__ beta,
                           const float* __restrict__ mean, const float* __restrict__ var,
                           float* __restrict__ scale, float* __restrict__ shift) {
  int i = blockIdx.x * blockDim.x + threadIdx.x;
  if (i < D) {
    float sc = gamma[i] * rsqrtf(var[i] + BN_EPS);
    scale[i] = sc;
    shift[i] = beta[i] - mean[i] * sc;
  }
}

// C[M,N] = op(A) @ Bw + bias. Tile 128x64, BK=32, 256 threads, 8x4 per thread.
// MODE 0: plain f32 A. MODE 1: A*p0[k]+p1[k] (BN fold). MODE 3: A is bf16.
template<int MODE, bool RELU>
__global__ __launch_bounds__(256)
void k_gemm(const float* __restrict__ A, const float* __restrict__ Bw,
            const float* __restrict__ bias, float* __restrict__ C,
            const float* __restrict__ p0, const float* __restrict__ p1,
            int M, int N, int K) {
  __shared__ float As[32][128]; // [k][m] transposed
  __shared__ float Bs[32][64];  // [k][n]
  const int t = threadIdx.x;
  const int tx = t & 15, ty = t >> 4;
  const int m0 = blockIdx.x * 128;
  const int n0 = blockIdx.y * 64;

  float acc[8][4];
#pragma unroll
  for (int i = 0; i < 8; ++i)
#pragma unroll
    for (int j = 0; j < 4; ++j) acc[i][j] = 0.f;

  const int am = t >> 1;       // 0..127
  const int ak = (t & 1) * 16; // 0 or 16
  const int bk = t >> 3;       // 0..31
  const int bn = (t & 7) * 8;  // 0..56

  for (int k0 = 0; k0 < K; k0 += 32) {
    __syncthreads();
    { // stage A (16 elems per thread)
      const int grow = m0 + am;
      const int gk = k0 + ak;
      float v[16];
      if (MODE == 0) {
        const float4* src = (const float4*)&A[(size_t)grow * K + gk];
#pragma unroll
        for (int i = 0; i < 4; ++i) {
          float4 f = src[i];
          v[4*i] = f.x; v[4*i+1] = f.y; v[4*i+2] = f.z; v[4*i+3] = f.w;
        }
      } else if (MODE == 1) {
        const float4* src = (const float4*)&A[(size_t)grow * K + gk];
        const float4* sc4 = (const float4*)&p0[gk];
        const float4* sh4 = (const float4*)&p1[gk];
#pragma unroll
        for (int i = 0; i < 4; ++i) {
          float4 f = src[i], sc = sc4[i], sh = sh4[i];
          v[4*i]   = fmaf(f.x, sc.x, sh.x);
          v[4*i+1] = fmaf(f.y, sc.y, sh.y);
          v[4*i+2] = fmaf(f.z, sc.z, sh.z);
          v[4*i+3] = fmaf(f.w, sc.w, sh.w);
        }
      } else { // MODE 3: bf16 A
        const unsigned short* A16 = (const unsigned short*)A;
        u16x8 u0 = *(const u16x8*)&A16[(size_t)grow * K + gk];
        u16x8 u1 = *(const u16x8*)&A16[(size_t)grow * K + gk + 8];
#pragma unroll
        for (int i = 0; i < 8; ++i) { v[i] = bf2f(u0[i]); v[8 + i] = bf2f(u1[i]); }
      }
#pragma unroll
      for (int i = 0; i < 16; ++i) As[ak + i][am] = v[i];
    }
    { // stage B (8 floats per thread)
      const float4* src = (const float4*)&Bw[(size_t)(k0 + bk) * N + n0 + bn];
      float4 f0 = src[0], f1 = src[1];
      *(float4*)&Bs[bk][bn] = f0;
      *(float4*)&Bs[bk][bn + 4] = f1;
    }
    __syncthreads();
#pragma unroll 8
    for (int kk = 0; kk < 32; ++kk) {
      float4 a0 = *(const float4*)&As[kk][ty * 4];
      float4 a1 = *(const float4*)&As[kk][64 + ty * 4];
      float4 b0 = *(const float4*)&Bs[kk][tx * 4];
      float av[8] = {a0.x, a0.y, a0.z, a0.w, a1.x, a1.y, a1.z, a1.w};
      float bv[4] = {b0.x, b0.y, b0.z, b0.w};
#pragma unroll
      for (int i = 0; i < 8; ++i)
#pragma unroll
        for (int j = 0; j < 4; ++j) acc[i][j] = fmaf(av[i], bv[j], acc[i][j]);
    }
  }
  const float4 bb4 = *(const float4*)&bias[n0 + tx * 4];
#pragma unroll
  for (int i = 0; i < 8; ++i) {
    const int row = m0 + ((i < 4) ? (ty * 4 + i) : (64 + ty * 4 + (i - 4)));
    float4 o;
    o.x = acc[i][0] + bb4.x; o.y = acc[i][1] + bb4.y;
    o.z = acc[i][2] + bb4.z; o.w = acc[i][3] + bb4.w;
    if (RELU) {
      o.x = fmaxf(o.x, 0.f); o.y = fmaxf(o.y, 0.f);
      o.z = fmaxf(o.z, 0.f); o.w = fmaxf(o.w, 0.f);
    }
    *(float4*)&C[(size_t)row * N + n0 + tx * 4] = o;
  }
}

// xq f32 [4096,1024] -> qhT bf16 [B,H,64dh,1024s]  (transpose per 64x64 tile)
__global__ __launch_bounds__(256)
void k_cvt(const float* __restrict__ xq, unsigned short* __restrict__ qhT) {
  __shared__ float Ls[64][65];
  const int t = threadIdx.x;
  const int b = blockIdx.x >> 4;
  const int sbase = (blockIdx.x & 15) * 64;
  const int h = blockIdx.y;
  { // load 64x64 f32 tile
    const int r = t >> 2, c0 = (t & 3) * 16;
#pragma unroll
    for (int i = 0; i < 4; ++i) {
      float4 f = *(const float4*)&xq[(size_t)(b * 1024 + sbase + r) * 1024 + h * 64 + c0 + 4 * i];
      Ls[r][c0 + 4 * i]     = f.x;
      Ls[r][c0 + 4 * i + 1] = f.y;
      Ls[r][c0 + 4 * i + 2] = f.z;
      Ls[r][c0 + 4 * i + 3] = f.w;
    }
  }
  __syncthreads();
  { // write transposed bf16
    const int d = t & 63, sc = (t >> 6) * 16;
    u16x8 o0, o1;
#pragma unroll
    for (int i = 0; i < 8; ++i) {
      o0[i] = f2bf(Ls[sc + i][d]);
      o1[i] = f2bf(Ls[sc + 8 + i][d]);
    }
    size_t obase = ((size_t)((b * 16 + h) * 64 + d)) * 1024 + sbase + sc;
    *(u16x8*)&qhT[obase] = o0;
    *(u16x8*)&qhT[obase + 8] = o1;
  }
}

// PASS 0: stats (sum_l, n_cnt, denom). PASS 1: attn write + pv (bf16, w_row-scaled).
// Block: (q-tile 64, h, b), 4 waves; wave w owns q rows [w*16, w*16+16).
// mfma_f32_16x16x32_bf16: A lane(row=l&15, k=(l>>4)*8+i), B lane(col=l&15, same k),
// D lane(col=l&15, row=(l>>4)*4+reg).
template<int PASS>
__global__ __launch_bounds__(256)
void k_attn_mfma(const float* __restrict__ xq, const int* __restrict__ mask,
                 const unsigned short* __restrict__ qhT, const float* __restrict__ w_row,
                 float* __restrict__ attn, unsigned short* __restrict__ pvb,
                 float* __restrict__ sum_l, float* __restrict__ n_cnt,
                 float* __restrict__ denom) {
  __shared__ float Lmf[64][64];        // mask tile, premultiplied by -1e9
  __shared__ unsigned short Pst[4][16][80]; // per-wave p strips (PASS 1), 16B-aligned pitch

  const int t = threadIdx.x;
  const int w = t >> 6, l = t & 63;
  const int l15 = l & 15, l4 = l >> 4;
  const int q0 = blockIdx.x * 64;
  const int h = blockIdx.y, b = blockIdx.z;
  const int bh = b * 16 + h;

  // Q fragments (held in regs for whole block)
  bf16x8 qa0, qa1;
  {
    const float* qp = &xq[((size_t)(b * 1024 + q0 + w * 16 + l15)) * 1024 + h * 64 + l4 * 8];
    float4 f0 = *(const float4*)qp, f1 = *(const float4*)(qp + 4);
    float4 g0 = *(const float4*)(qp + 32), g1 = *(const float4*)(qp + 36);
    qa0 = pack8(f0, f1);
    qa1 = pack8(g0, g1);
  }

  float wsc_r[4];
  float wsc_q = 0.f;
  if (PASS == 1) {
#pragma unroll
    for (int r = 0; r < 4; ++r)
      wsc_r[r] = w_row[(size_t)bh * 1024 + q0 + w * 16 + l4 * 4 + r];
    wsc_q = w_row[(size_t)bh * 1024 + q0 + w * 16 + (l >> 2)];
  }

  float lsum[4] = {0, 0, 0, 0}, dsum[4] = {0, 0, 0, 0};
  int cnt = 0;
  f32x4 vacc[4];
#pragma unroll
  for (int c = 0; c < 4; ++c) vacc[c] = (f32x4){0.f, 0.f, 0.f, 0.f};

  const int mrow = t >> 2, mc0 = (t & 3) * 16;

  for (int k0 = 0; k0 < 1024; k0 += 64) {
    __syncthreads(); // everyone done with previous Lmf
    { // cooperative mask tile load
      const int* mp = &mask[((size_t)b * 1024 + q0 + mrow) * 1024 + k0 + mc0];
      int4 m0 = *(const int4*)mp, m1 = *(const int4*)(mp + 4);
      int4 m2 = *(const int4*)(mp + 8), m3 = *(const int4*)(mp + 12);
      if (PASS == 0)
        cnt += (m0.x + m0.y + m0.z + m0.w) + (m1.x + m1.y + m1.z + m1.w) +
               (m2.x + m2.y + m2.z + m2.w) + (m3.x + m3.y + m3.z + m3.w);
      *(float4*)&Lmf[mrow][mc0]      = make_float4(NEG_BIG * m0.x, NEG_BIG * m0.y, NEG_BIG * m0.z, NEG_BIG * m0.w);
      *(float4*)&Lmf[mrow][mc0 + 4]  = make_float4(NEG_BIG * m1.x, NEG_BIG * m1.y, NEG_BIG * m1.z, NEG_BIG * m1.w);
      *(float4*)&Lmf[mrow][mc0 + 8]  = make_float4(NEG_BIG * m2.x, NEG_BIG * m2.y, NEG_BIG * m2.z, NEG_BIG * m2.w);
      *(float4*)&Lmf[mrow][mc0 + 12] = make_float4(NEG_BIG * m3.x, NEG_BIG * m3.y, NEG_BIG * m3.z, NEG_BIG * m3.w);
    }
    __syncthreads();

    // QK^T: wave computes 16q x 64key strip (4 col-tiles, dh=64 in 2 mfmas)
    f32x4 lacc[4];
#pragma unroll
    for (int c = 0; c < 4; ++c) {
      const float* kp = &xq[((size_t)(b * 1024 + k0 + c * 16 + l15)) * 1024 + h * 64 + l4 * 8];
      float4 f0 = *(const float4*)kp, f1 = *(const float4*)(kp + 4);
      float4 g0 = *(const float4*)(kp + 32), g1 = *(const float4*)(kp + 36);
      bf16x8 kb0 = pack8(f0, f1), kb1 = pack8(g0, g1);
      f32x4 z = (f32x4){0.f, 0.f, 0.f, 0.f};
      z = __builtin_amdgcn_mfma_f32_16x16x32_bf16(qa0, kb0, z, 0, 0, 0);
      z = __builtin_amdgcn_mfma_f32_16x16x32_bf16(qa1, kb1, z, 0, 0, 0);
      lacc[c] = z;
    }

    if (PASS == 0) {
#pragma unroll
      for (int c = 0; c < 4; ++c)
#pragma unroll
        for (int r = 0; r < 4; ++r) {
          float lv = lacc[c][r] * 0.125f;
          lsum[r] += lv;
          dsum[r] += __expf(lv + Lmf[w * 16 + l4 * 4 + r][c * 16 + l15]);
        }
    } else {
#pragma unroll
      for (int c = 0; c < 4; ++c)
#pragma unroll
        for (int r = 0; r < 4; ++r) {
          float lv = lacc[c][r] * 0.125f;
          float p = __expf(lv + Lmf[w * 16 + l4 * 4 + r][c * 16 + l15]);
          Pst[w][l4 * 4 + r][c * 16 + l15] = f2bf(p);
        }
      // attn write: lane covers q=l>>2 (strip row), 16 keys at (l&3)*16
      {
        const int aq = l >> 2, kc0 = (l & 3) * 16;
        u16x8 pa0 = *(const u16x8*)&Pst[w][aq][kc0];
        u16x8 pa1 = *(const u16x8*)&Pst[w][aq][kc0 + 8];
        float* ap = &attn[((size_t)bh * 1024 + q0 + w * 16 + aq) * 1024 + k0 + kc0];
        float4 o;
        o.x = bf2f(pa0[0]) * wsc_q; o.y = bf2f(pa0[1]) * wsc_q;
        o.z = bf2f(pa0[2]) * wsc_q; o.w = bf2f(pa0[3]) * wsc_q;
        *(float4*)ap = o;
        o.x = bf2f(pa0[4]) * wsc_q; o.y = bf2f(pa0[5]) * wsc_q;
        o.z = bf2f(pa0[6]) * wsc_q; o.w = bf2f(pa0[7]) * wsc_q;
        *(float4*)(ap + 4) = o;
        o.x = bf2f(pa1[0]) * wsc_q; o.y = bf2f(pa1[1]) * wsc_q;
        o.z = bf2f(pa1[2]) * wsc_q; o.w = bf2f(pa1[3]) * wsc_q;
        *(float4*)(ap + 8) = o;
        o.x = bf2f(pa1[4]) * wsc_q; o.y = bf2f(pa1[5]) * wsc_q;
        o.z = bf2f(pa1[6]) * wsc_q; o.w = bf2f(pa1[7]) * wsc_q;
        *(float4*)(ap + 12) = o;
      }
      // PV: out[q][dv] += p[q][key] * qh[key][dv], keys of this tile
#pragma unroll
      for (int kk = 0; kk < 2; ++kk) {
        bf16x8 pa = *(const bf16x8*)&Pst[w][l15][kk * 32 + l4 * 8];
#pragma unroll
        for (int c = 0; c < 4; ++c) {
          bf16x8 vb = *(const bf16x8*)&qhT[((size_t)(bh * 64 + c * 16 + l15)) * 1024 + k0 + kk * 32 + l4 * 8];
          vacc[c] = __builtin_amdgcn_mfma_f32_16x16x32_bf16(pa, vb, vacc[c], 0, 0, 0);
        }
      }
    }
  }

  if (PASS == 0) {
#pragma unroll
    for (int r = 0; r < 4; ++r) {
      float a = lsum[r], d2 = dsum[r];
#pragma unroll
      for (int m = 1; m < 16; m <<= 1) {
        a += __shfl_xor(a, m, 64);
        d2 += __shfl_xor(d2, m, 64);
      }
      if (l15 == 0) {
        const size_t row = (size_t)bh * 1024 + q0 + w * 16 + l4 * 4 + r;
        sum_l[row] = a;
        denom[row] = d2;
      }
    }
    int c2 = cnt;
    c2 += __shfl_xor(c2, 1, 64);
    c2 += __shfl_xor(c2, 2, 64);
    if ((t & 3) == 0) n_cnt[(size_t)bh * 1024 + q0 + (t >> 2)] = (float)c2;
  } else {
#pragma unroll
    for (int c = 0; c < 4; ++c)
#pragma unroll
      for (int r = 0; r < 4; ++r)
        pvb[(size_t)(b * 1024 + q0 + w * 16 + l4 * 4 + r) * 1024 + h * 64 + c * 16 + l15] =
            f2bf(vacc[c][r] * wsc_r[r]);
  }
}

// per (b,h): w_within over queries (f64) -> w_row = w_within * (1/16) / denom
__global__ __launch_bounds__(256)
void k_wwithin(const float* __restrict__ sum_l, const float* __restrict__ n_mask,
               const float* __restrict__ denom, float* __restrict__ w_row) {
  __shared__ double buf[1024];
  __shared__ double red[256];
  __shared__ double sh_mu, sh_sd, sh_zm, sh_es;
  const int bh = blockIdx.x, t = threadIdx.x;
  const int base = bh << 10;
  double part = 0;
  for (int q2 = t; q2 < 1024; q2 += 256) {
    double last = ((double)sum_l[base + q2] - 1e9 * (double)n_mask[base + q2]) * (1.0 / 1024.0);
    buf[q2] = last; part += last;
  }
  red[t] = part; __syncthreads();
  for (int s2 = 128; s2 > 0; s2 >>= 1) { if (t < s2) red[t] += red[t + s2]; __syncthreads(); }
  if (t == 0) sh_mu = red[0] * (1.0 / 1024.0);
  __syncthreads();
  const double mu = sh_mu;
  part = 0;
  for (int q2 = t; q2 < 1024; q2 += 256) { double d = buf[q2] - mu; part += d * d; }
  red[t] = part; __syncthreads();
  for (int s2 = 128; s2 > 0; s2 >>= 1) { if (t < s2) red[t] += red[t + s2]; __syncthreads(); }
  if (t == 0) sh_sd = sqrt(red[0] * (1.0 / 1024.0));
  __syncthreads();
  const double dn = sh_sd * 2.0 + 1e-10;
  part = -1e300;
  for (int q2 = t; q2 < 1024; q2 += 256) {
    double z = (buf[q2] - mu) / dn;
    buf[q2] = z;
    part = fmax(part, z);
  }
  red[t] = part; __syncthreads();
  for (int s2 = 128; s2 > 0; s2 >>= 1) { if (t < s2) red[t] = fmax(red[t], red[t + s2]); __syncthreads(); }
  if (t == 0) sh_zm = red[0];
  __syncthreads();
  const double zm = sh_zm;
  part = 0;
  for (int q2 = t; q2 < 1024; q2 += 256) {
    double e = exp(buf[q2] - zm);
    buf[q2] = e; part += e;
  }
  red[t] = part; __syncthreads();
  for (int s2 = 128; s2 > 0; s2 >>= 1) { if (t < s2) red[t] += red[t + s2]; __syncthreads(); }
  if (t == 0) sh_es = red[0];
  __syncthreads();
  const double tot = sh_es;
  for (int q2 = t; q2 < 1024; q2 += 256) {
    w_row[base + q2] = (float)(buf[q2] / tot * 0.0625 / (double)denom[base + q2]);
  }
}

extern "C" void kernel_launch(void* const* d_in, const int* in_sizes, int n_in,
                              void* d_out, int out_size, void* d_ws, size_t ws_size,
                              hipStream_t stream) {
  const float* q      = (const float*)d_in[0];
  const int*   mask   = (const int*)d_in[3];
  const float* q_gamma = (const float*)d_in[5];
  const float* q_beta  = (const float*)d_in[6];
  const float* q_mean  = (const float*)d_in[7];
  const float* q_var   = (const float*)d_in[8];
  const float* Wq  = (const float*)d_in[9];
  const float* bq  = (const float*)d_in[10];
  const float* Wqq = (const float*)d_in[11];
  const float* bqq = (const float*)d_in[12];
  const float* Wo  = (const float*)d_in[13];
  const float* bo  = (const float*)d_in[14];

  float* out  = (float*)d_out;                          // [4096,1024]
  float* attn = (float*)d_out + (size_t)N_ROWS * D;     // [B,H,S,S]

  char* ws = (char*)d_ws;
  // [0,16MB): x1 f32 (gemm1->gemm2 only); afterwards:
  //   [0,8MB): qhT bf16, [8MB,16MB): pv bf16
  float* x1            = (float*)ws;
  unsigned short* qhT  = (unsigned short*)ws;
  unsigned short* pvb  = (unsigned short*)(ws + (8u << 20));
  float* sum_l  = (float*)(ws + (16u << 20));
  float* n_cnt  = sum_l + 65536;
  float* denom  = n_cnt + 65536;
  float* w_row  = denom + 65536;
  float* bnsc   = w_row + 65536;
  float* bnsh   = bnsc + 1024;

  float* xq = out; // out-region doubles as qh scratch until the final GEMM

  k_bnparams<<<4, 256, 0, stream>>>(q_gamma, q_beta, q_mean, q_var, bnsc, bnsh);

  dim3 g1(N_ROWS / 128, D / 64);
  k_gemm<1, true><<<g1, 256, 0, stream>>>(q, Wq, bq, x1, bnsc, bnsh, N_ROWS, D, D);
  k_gemm<0, false><<<g1, 256, 0, stream>>>(x1, Wqq, bqq, xq, nullptr, nullptr, N_ROWS, D, D);

  k_cvt<<<dim3(64, 16), 256, 0, stream>>>(xq, qhT);

  dim3 ga(S / 64, H, Bz);
  k_attn_mfma<0><<<ga, 256, 0, stream>>>(xq, mask, nullptr, nullptr, nullptr, nullptr,
                                         sum_l, n_cnt, denom);

  k_wwithin<<<Bz * H, 256, 0, stream>>>(sum_l, n_cnt, denom, w_row);

  k_attn_mfma<1><<<ga, 256, 0, stream>>>(xq, mask, qhT, w_row, attn, pvb,
                                         nullptr, nullptr, nullptr);

  k_gemm<3, false><<<g1, 256, 0, stream>>>((const float*)pvb, Wo, bo, out,
                                           nullptr, nullptr, N_ROWS, D, D);
}

// Round 4
// 384.218 us; speedup vs baseline: 1.9261x; 1.9261x over previous
//
#include <hip/hip_runtime.h>
#include <math.h>

// MultiHeadAttention_22067541967542 — round 4: bf16 MFMA everywhere.
// B=4, S=1024, D=1024, H=16, dh=64. k/v/is_training dead.
// w_betw == 1/16 exactly (f32 absorption in reference, round-2 analysis).
// Pipeline:
//   k_bnparams
//   k_gemm_bf<0,relu,bf16out>: x1b = relu(BN(q)@Wq+bq)   bf16 [ws 0..8MB)
//   k_gemm_bf<1,-,f32out>:     xq  = x1b@Wqq+bqq         f32  [d_out out-region]
//   k_cvt:     qhT bf16 [B,H,dh,S]                       [ws 8..16MB)
//   k_masksum: n_cnt2[b,q] = row-sum of mask             (head-independent)
//   k_suml:    sum_l[bh,q] = dot(qh[q], colsum[bh])/8    (factorized: O(S*dh))
//   k_attn2<0>: QK^T (staged bf16 LDS) -> denom only
//   k_wwithin:  f64 z-norm softmax -> w_row = w_within/16/denom
//   k_attn2<1>: recompute QK^T -> attn=p*w_row (direct from D-regs), PV -> pvb
//   k_gemm_bf<1,-,f32out>: out = pvb@Wo+bo
// LDS discipline: all tiles 128B-row + XOR swizzle (byte ^= (row&7)<<4);
// b128 fragment reads at the 8-phase b128 floor.

constexpr int Bz = 4, S = 1024, D = 1024, H = 16, DH = 64;
constexpr int N_ROWS = Bz * S; // 4096
#define BN_EPS 1e-3f
#define NEG_BIG -1e9f

typedef __attribute__((ext_vector_type(8))) short bf16x8;
typedef __attribute__((ext_vector_type(8))) unsigned short u16x8;
typedef __attribute__((ext_vector_type(4))) float f32x4;

__device__ inline unsigned short f2bf(float f) {
  union { float f; unsigned int u; } v; v.f = f;
  unsigned int u = v.u;
  return (unsigned short)((u + 0x7FFFu + ((u >> 16) & 1u)) >> 16); // RNE
}
__device__ inline float bf2f(unsigned short h) {
  union { unsigned int u; float f; } v; v.u = ((unsigned int)h) << 16;
  return v.f;
}
__device__ inline bf16x8 pack8(float4 a, float4 b) {
  bf16x8 v;
  v[0] = (short)f2bf(a.x); v[1] = (short)f2bf(a.y);
  v[2] = (short)f2bf(a.z); v[3] = (short)f2bf(a.w);
  v[4] = (short)f2bf(b.x); v[5] = (short)f2bf(b.y);
  v[6] = (short)f2bf(b.z); v[7] = (short)f2bf(b.w);
  return v;
}
__device__ inline float4 bnf(float4 f, float4 s, float4 sh) {
  return make_float4(fmaf(f.x, s.x, sh.x), fmaf(f.y, s.y, sh.y),
                     fmaf(f.z, s.z, sh.z), fmaf(f.w, s.w, sh.w));
}

__global__ void k_bnparams(const float* __restrict__ gamma, const float* __restrict__ beta,
                           const float* __restrict__ mean, const float* __restrict__ var,
                           float* __restrict__ scale, float* __restrict__ shift) {
  int i = blockIdx.x * blockDim.x + threadIdx.x;
  if (i < D) {
    float sc = gamma[i] * rsqrtf(var[i] + BN_EPS);
    scale[i] = sc;
    shift[i] = beta[i] - mean[i] * sc;
  }
}

// bf16 MFMA GEMM: C[M=4096,N=1024] = op(A)@Bw + bias. Tile 128x64, BK=32,
// 256 thr (4 waves 2x2, wave-tile 64x32). AMODE 0: A f32 + BN fold; 1: A bf16.
// Bw is f32 [K,N], transpose-staged to Bs[n][k] bf16.
template<int AMODE, bool RELU, bool OUTBF>
__global__ __launch_bounds__(256)
void k_gemm_bf(const void* __restrict__ Asrc, const float* __restrict__ Bw,
               const float* __restrict__ bias, void* __restrict__ Cdst,
               const float* __restrict__ bnsc, const float* __restrict__ bnsh) {
  __shared__ unsigned short As[128 * 32]; // [m][k], 64B rows, swz (row&3)<<4
  __shared__ unsigned short Bs[64 * 40];  // [n][k], 80B pitch, swz (n&3)<<4
  const int t = threadIdx.x;
  const int w = t >> 6, l = t & 63, l15 = l & 15, l4 = l >> 4;
  const int m0 = blockIdx.x * 128, n0 = blockIdx.y * 64;
  const int wm = (w >> 1) * 64, wn = (w & 1) * 32;

  f32x4 acc[4][2];
#pragma unroll
  for (int i = 0; i < 4; ++i)
#pragma unroll
    for (int j = 0; j < 2; ++j) acc[i][j] = (f32x4){0.f, 0.f, 0.f, 0.f};

  const int ar = t >> 1, ak = (t & 1) * 16; // A stage: 16 elems
  const int bn_ = t & 63, bk_ = (t >> 6) * 8; // B stage: 8 elems (transpose)

  for (int k0 = 0; k0 < 1024; k0 += 32) {
    __syncthreads();
    { // stage A -> bf16 LDS
      bf16x8 lo, hi;
      if (AMODE == 0) {
        const float* ap = &((const float*)Asrc)[(size_t)(m0 + ar) * 1024 + k0 + ak];
        float4 f0 = *(const float4*)ap, f1 = *(const float4*)(ap + 4);
        float4 f2 = *(const float4*)(ap + 8), f3 = *(const float4*)(ap + 12);
        const float4 s0 = *(const float4*)&bnsc[k0 + ak], s1 = *(const float4*)&bnsc[k0 + ak + 4];
        const float4 s2 = *(const float4*)&bnsc[k0 + ak + 8], s3 = *(const float4*)&bnsc[k0 + ak + 12];
        const float4 h0 = *(const float4*)&bnsh[k0 + ak], h1 = *(const float4*)&bnsh[k0 + ak + 4];
        const float4 h2 = *(const float4*)&bnsh[k0 + ak + 8], h3 = *(const float4*)&bnsh[k0 + ak + 12];
        lo = pack8(bnf(f0, s0, h0), bnf(f1, s1, h1));
        hi = pack8(bnf(f2, s2, h2), bnf(f3, s3, h3));
      } else {
        const unsigned short* ap = &((const unsigned short*)Asrc)[(size_t)(m0 + ar) * 1024 + k0 + ak];
        lo = *(const bf16x8*)ap;
        hi = *(const bf16x8*)(ap + 8);
      }
      char* dst = (char*)&As[ar * 32];
      const int sw = (ar & 3) << 4;
      *(bf16x8*)(dst + ((ak * 2) ^ sw)) = lo;
      *(bf16x8*)(dst + ((ak * 2 + 16) ^ sw)) = hi;
    }
    { // stage B transposed (scalar f32 loads, coalesced across lanes)
      u16x8 tv;
#pragma unroll
      for (int j = 0; j < 8; ++j)
        tv[j] = f2bf(Bw[(size_t)(k0 + bk_ + j) * 1024 + n0 + bn_]);
      char* dst = (char*)&Bs[bn_ * 40];
      *(u16x8*)(dst + ((bk_ * 2) ^ ((bn_ & 3) << 4))) = tv;
    }
    __syncthreads();
    bf16x8 af[4], bfr[2];
#pragma unroll
    for (int bm = 0; bm < 4; ++bm) {
      const int row = wm + bm * 16 + l15;
      af[bm] = *(const bf16x8*)((const char*)&As[row * 32] + ((l4 * 16) ^ ((row & 3) << 4)));
    }
#pragma unroll
    for (int bn = 0; bn < 2; ++bn) {
      const int n = wn + bn * 16 + l15;
      bfr[bn] = *(const bf16x8*)((const char*)&Bs[n * 40] + ((l4 * 16) ^ ((n & 3) << 4)));
    }
#pragma unroll
    for (int bm = 0; bm < 4; ++bm)
#pragma unroll
      for (int bn = 0; bn < 2; ++bn)
        acc[bm][bn] = __builtin_amdgcn_mfma_f32_16x16x32_bf16(af[bm], bfr[bn], acc[bm][bn], 0, 0, 0);
  }
  float bv[2];
#pragma unroll
  for (int bn = 0; bn < 2; ++bn) bv[bn] = bias[n0 + wn + bn * 16 + l15];
#pragma unroll
  for (int bm = 0; bm < 4; ++bm)
#pragma unroll
    for (int bn = 0; bn < 2; ++bn)
#pragma unroll
      for (int r = 0; r < 4; ++r) {
        float v = acc[bm][bn][r] + bv[bn];
        if (RELU) v = fmaxf(v, 0.f);
        const size_t idx = (size_t)(m0 + wm + bm * 16 + l4 * 4 + r) * 1024 + n0 + wn + bn * 16 + l15;
        if (OUTBF) ((unsigned short*)Cdst)[idx] = f2bf(v);
        else ((float*)Cdst)[idx] = v;
      }
}

// xq f32 [4096,1024] -> qhT bf16 [B,H,dh=64,S=1024]
__global__ __launch_bounds__(256)
void k_cvt(const float* __restrict__ xq, unsigned short* __restrict__ qhT) {
  __shared__ float Ls[64][65];
  const int t = threadIdx.x;
  const int b = blockIdx.x >> 4;
  const int sbase = (blockIdx.x & 15) * 64;
  const int h = blockIdx.y;
  {
    const int r = t >> 2, c0 = (t & 3) * 16;
#pragma unroll
    for (int i = 0; i < 4; ++i) {
      float4 f = *(const float4*)&xq[(size_t)(b * 1024 + sbase + r) * 1024 + h * 64 + c0 + 4 * i];
      Ls[r][c0 + 4 * i] = f.x; Ls[r][c0 + 4 * i + 1] = f.y;
      Ls[r][c0 + 4 * i + 2] = f.z; Ls[r][c0 + 4 * i + 3] = f.w;
    }
  }
  __syncthreads();
  {
    const int d = t & 63, sc = (t >> 6) * 16;
    u16x8 o0, o1;
#pragma unroll
    for (int i = 0; i < 8; ++i) {
      o0[i] = f2bf(Ls[sc + i][d]);
      o1[i] = f2bf(Ls[sc + 8 + i][d]);
    }
    size_t obase = ((size_t)((b * 16 + h) * 64 + d)) * 1024 + sbase + sc;
    *(u16x8*)&qhT[obase] = o0;
    *(u16x8*)&qhT[obase + 8] = o1;
  }
}

// n_cnt2[b*1024+q] = sum_k mask[b,q,k]  (mask is head-independent)
__global__ __launch_bounds__(256)
void k_masksum(const int* __restrict__ mask, float* __restrict__ n_cnt2) {
  const int t = threadIdx.x;
  const int row = blockIdx.x * 64 + (t >> 2);
  const int4* mp = (const int4*)&mask[(size_t)row * 1024 + (t & 3) * 256];
  int s = 0;
#pragma unroll 8
  for (int i = 0; i < 64; ++i) { int4 m = mp[i]; s += (m.x + m.y) + (m.z + m.w); }
  s += __shfl_xor(s, 1, 64);
  s += __shfl_xor(s, 2, 64);
  if ((t & 3) == 0) n_cnt2[row] = (float)s;
}

// sum_l[bh,q] = dot(xq_head_row[q], colsum[bh]) / 8   (factorized row-sum of logits)
__global__ __launch_bounds__(256)
void k_suml(const float* __restrict__ xq, float* __restrict__ sum_l) {
  __shared__ float red[256];
  __shared__ float cs[64];
  const int h = blockIdx.x, b = blockIdx.y;
  const int t = threadIdx.x;
  const int d = t & 63, qs = t >> 6;
  float part = 0.f;
  for (int q = qs * 256; q < qs * 256 + 256; ++q)
    part += xq[(size_t)(b * 1024 + q) * 1024 + h * 64 + d];
  red[t] = part;
  __syncthreads();
  if (t < 64) cs[t] = (red[t] + red[64 + t]) + (red[128 + t] + red[192 + t]);
  __syncthreads();
  const int bh = b * 16 + h;
#pragma unroll
  for (int j = 0; j < 4; ++j) {
    const int q = t + j * 256;
    const float* row = &xq[(size_t)(b * 1024 + q) * 1024 + h * 64];
    float s = 0.f;
#pragma unroll
    for (int dd = 0; dd < 64; dd += 4) {
      float4 f = *(const float4*)&row[dd];
      s += f.x * cs[dd] + f.y * cs[dd + 1] + f.z * cs[dd + 2] + f.w * cs[dd + 3];
    }
    sum_l[(size_t)bh * 1024 + q] = s * 0.125f;
  }
}

// PASS 0: denom only. PASS 1: attn (=p*w_row, direct from D-regs) + pvb.
// Block (q-tile 64, h, b); wave w owns q rows [w*16, w*16+16).
// K tile staged once per block into XOR-swizzled bf16 LDS.
template<int PASS>
__global__ __launch_bounds__(256)
void k_attn2(const float* __restrict__ xq, const int* __restrict__ mask,
             const unsigned short* __restrict__ qhT, const float* __restrict__ w_row,
             float* __restrict__ attn, unsigned short* __restrict__ pvb,
             float* __restrict__ denom) {
  __shared__ unsigned short Ks[64 * 64];   // [key][dh], 128B rows, swz (key&7)<<4
  __shared__ unsigned short Pst[4][16 * 64]; // per-wave [q][key], 128B rows, swz

  const int t = threadIdx.x;
  const int w = t >> 6, l = t & 63;
  const int l15 = l & 15, l4 = l >> 4;
  const int q0 = blockIdx.x * 64;
  const int h = blockIdx.y, b = blockIdx.z;
  const int bh = b * 16 + h;

  // Q fragments from global f32 (once per block)
  bf16x8 qa0, qa1;
  {
    const float* qp = &xq[((size_t)(b * 1024 + q0 + w * 16 + l15)) * 1024 + h * 64 + l4 * 8];
    float4 f0 = *(const float4*)qp, f1 = *(const float4*)(qp + 4);
    float4 g0 = *(const float4*)(qp + 32), g1 = *(const float4*)(qp + 36);
    qa0 = pack8(f0, f1);
    qa1 = pack8(g0, g1);
  }

  float wsc[4];
  if (PASS == 1) {
#pragma unroll
    for (int r = 0; r < 4; ++r)
      wsc[r] = w_row[(size_t)bh * 1024 + q0 + w * 16 + l4 * 4 + r];
  }

  float dsum[4] = {0.f, 0.f, 0.f, 0.f};
  f32x4 vacc[4];
#pragma unroll
  for (int c = 0; c < 4; ++c) vacc[c] = (f32x4){0.f, 0.f, 0.f, 0.f};

  const int sk = t >> 2, sd = (t & 3) * 16; // staging: key, dh-chunk
  const int ssw = (sk & 7) << 4;

  for (int k0 = 0; k0 < 1024; k0 += 64) {
    __syncthreads(); // previous tile consumed
    { // cooperative K-tile stage: f32 -> bf16, swizzled
      const float* kp = &xq[((size_t)(b * 1024 + k0 + sk)) * 1024 + h * 64 + sd];
      float4 f0 = *(const float4*)kp, f1 = *(const float4*)(kp + 4);
      float4 f2 = *(const float4*)(kp + 8), f3 = *(const float4*)(kp + 12);
      char* dst = (char*)&Ks[sk * 64];
      *(bf16x8*)(dst + ((sd * 2) ^ ssw)) = pack8(f0, f1);
      *(bf16x8*)(dst + ((sd * 2 + 16) ^ ssw)) = pack8(f2, f3);
    }
    __syncthreads();

    // QK^T: 4 col-tiles x (dh=64 in 2 mfmas)
    f32x4 lacc[4];
#pragma unroll
    for (int c = 0; c < 4; ++c) {
      const char* kb = (const char*)&Ks[(c * 16 + l15) * 64];
      const int rsw = (l15 & 7) << 4;
      bf16x8 kb0 = *(const bf16x8*)(kb + ((l4 * 16) ^ rsw));
      bf16x8 kb1 = *(const bf16x8*)(kb + ((64 + l4 * 16) ^ rsw));
      f32x4 z = (f32x4){0.f, 0.f, 0.f, 0.f};
      z = __builtin_amdgcn_mfma_f32_16x16x32_bf16(qa0, kb0, z, 0, 0, 0);
      z = __builtin_amdgcn_mfma_f32_16x16x32_bf16(qa1, kb1, z, 0, 0, 0);
      lacc[c] = z;
    }

    // mask direct from global (per-lane), exp, then attn/Pst or denom
    int mrr[4][4];
#pragma unroll
    for (int c = 0; c < 4; ++c)
#pragma unroll
      for (int r = 0; r < 4; ++r)
        mrr[c][r] = mask[((size_t)(b * 1024 + q0 + w * 16 + l4 * 4 + r)) * 1024 + k0 + c * 16 + l15];

#pragma unroll
    for (int c = 0; c < 4; ++c) {
#pragma unroll
      for (int r = 0; r < 4; ++r) {
        float p = __expf(fmaf((float)mrr[c][r], NEG_BIG, lacc[c][r] * 0.125f));
        if (PASS == 0) {
          dsum[r] += p;
        } else {
          attn[((size_t)(bh * 1024 + q0 + w * 16 + l4 * 4 + r)) * 1024 + k0 + c * 16 + l15] =
              p * wsc[r];
          const int qq = l4 * 4 + r;
          *(unsigned short*)((char*)&Pst[w][qq * 64] +
                             (((c * 16 + l15) * 2) ^ ((qq & 7) << 4))) = f2bf(p);
        }
      }
    }

    if (PASS == 1) {
      // PV: A = Pst row q=l15 (wave-private, lgkmcnt-ordered), B = qhT global
#pragma unroll
      for (int kk = 0; kk < 2; ++kk) {
        const char* pb = (const char*)&Pst[w][l15 * 64];
        bf16x8 pa = *(const bf16x8*)(pb + ((kk * 64 + l4 * 16) ^ ((l15 & 7) << 4)));
#pragma unroll
        for (int c = 0; c < 4; ++c) {
          bf16x8 vb = *(const bf16x8*)&qhT[((size_t)(bh * 64 + c * 16 + l15)) * 1024 +
                                           k0 + kk * 32 + l4 * 8];
          vacc[c] = __builtin_amdgcn_mfma_f32_16x16x32_bf16(pa, vb, vacc[c], 0, 0, 0);
        }
      }
    }
  }

  if (PASS == 0) {
#pragma unroll
    for (int r = 0; r < 4; ++r) {
      float d2 = dsum[r];
#pragma unroll
      for (int m = 1; m < 16; m <<= 1) d2 += __shfl_xor(d2, m, 64);
      if (l15 == 0)
        denom[(size_t)bh * 1024 + q0 + w * 16 + l4 * 4 + r] = d2;
    }
  } else {
#pragma unroll
    for (int c = 0; c < 4; ++c)
#pragma unroll
      for (int r = 0; r < 4; ++r)
        pvb[(size_t)(b * 1024 + q0 + w * 16 + l4 * 4 + r) * 1024 + h * 64 + c * 16 + l15] =
            f2bf(vacc[c][r] * wsc[r]);
  }
}

// per (b,h): w_within over queries (f64) -> w_row = w_within * (1/16) / denom
__global__ __launch_bounds__(256)
void k_wwithin(const float* __restrict__ sum_l, const float* __restrict__ n_cnt2,
               const float* __restrict__ denom, float* __restrict__ w_row) {
  __shared__ double buf[1024];
  __shared__ double red[256];
  __shared__ double sh_mu, sh_sd, sh_zm, sh_es;
  const int bh = blockIdx.x, t = threadIdx.x;
  const int base = bh << 10;
  const int nbase = (bh >> 4) << 10;
  double part = 0;
  for (int q2 = t; q2 < 1024; q2 += 256) {
    double last = ((double)sum_l[base + q2] - 1e9 * (double)n_cnt2[nbase + q2]) * (1.0 / 1024.0);
    buf[q2] = last; part += last;
  }
  red[t] = part; __syncthreads();
  for (int s2 = 128; s2 > 0; s2 >>= 1) { if (t < s2) red[t] += red[t + s2]; __syncthreads(); }
  if (t == 0) sh_mu = red[0] * (1.0 / 1024.0);
  __syncthreads();
  const double mu = sh_mu;
  part = 0;
  for (int q2 = t; q2 < 1024; q2 += 256) { double d = buf[q2] - mu; part += d * d; }
  red[t] = part; __syncthreads();
  for (int s2 = 128; s2 > 0; s2 >>= 1) { if (t < s2) red[t] += red[t + s2]; __syncthreads(); }
  if (t == 0) sh_sd = sqrt(red[0] * (1.0 / 1024.0));
  __syncthreads();
  const double dn = sh_sd * 2.0 + 1e-10;
  part = -1e300;
  for (int q2 = t; q2 < 1024; q2 += 256) {
    double z = (buf[q2] - mu) / dn;
    buf[q2] = z;
    part = fmax(part, z);
  }
  red[t] = part; __syncthreads();
  for (int s2 = 128; s2 > 0; s2 >>= 1) { if (t < s2) red[t] = fmax(red[t], red[t + s2]); __syncthreads(); }
  if (t == 0) sh_zm = red[0];
  __syncthreads();
  const double zm = sh_zm;
  part = 0;
  for (int q2 = t; q2 < 1024; q2 += 256) {
    double e = exp(buf[q2] - zm);
    buf[q2] = e; part += e;
  }
  red[t] = part; __syncthreads();
  for (int s2 = 128; s2 > 0; s2 >>= 1) { if (t < s2) red[t] += red[t + s2]; __syncthreads(); }
  if (t == 0) sh_es = red[0];
  __syncthreads();
  const double tot = sh_es;
  for (int q2 = t; q2 < 1024; q2 += 256) {
    w_row[base + q2] = (float)(buf[q2] / tot * 0.0625 / (double)denom[base + q2]);
  }
}

extern "C" void kernel_launch(void* const* d_in, const int* in_sizes, int n_in,
                              void* d_out, int out_size, void* d_ws, size_t ws_size,
                              hipStream_t stream) {
  const float* q      = (const float*)d_in[0];
  const int*   mask   = (const int*)d_in[3];
  const float* q_gamma = (const float*)d_in[5];
  const float* q_beta  = (const float*)d_in[6];
  const float* q_mean  = (const float*)d_in[7];
  const float* q_var   = (const float*)d_in[8];
  const float* Wq  = (const float*)d_in[9];
  const float* bq  = (const float*)d_in[10];
  const float* Wqq = (const float*)d_in[11];
  const float* bqq = (const float*)d_in[12];
  const float* Wo  = (const float*)d_in[13];
  const float* bo  = (const float*)d_in[14];

  float* out  = (float*)d_out;                          // [4096,1024]
  float* attn = (float*)d_out + (size_t)N_ROWS * D;     // [B,H,S,S]

  char* ws = (char*)d_ws;
  // [0,8MB): x1b bf16 (gemm1->gemm2), later pvb bf16 (attn pass1 -> gemm3)
  // [8,16MB): qhT bf16
  // [16MB..): stats (~0.81 MB, within proven footprint)
  unsigned short* x1b = (unsigned short*)ws;
  unsigned short* pvb = (unsigned short*)ws;
  unsigned short* qhT = (unsigned short*)(ws + (8u << 20));
  float* bnsc   = (float*)(ws + (16u << 20));
  float* bnsh   = bnsc + 1024;
  float* sum_l  = bnsh + 1024;
  float* denom  = sum_l + 65536;
  float* w_row  = denom + 65536;
  float* n_cnt2 = w_row + 65536;

  float* xq = out; // out-region doubles as qh scratch until the final GEMM

  k_bnparams<<<4, 256, 0, stream>>>(q_gamma, q_beta, q_mean, q_var, bnsc, bnsh);

  dim3 gg(32, 16);
  k_gemm_bf<0, true, true><<<gg, 256, 0, stream>>>(q, Wq, bq, x1b, bnsc, bnsh);
  k_gemm_bf<1, false, false><<<gg, 256, 0, stream>>>(x1b, Wqq, bqq, xq, nullptr, nullptr);

  k_cvt<<<dim3(64, 16), 256, 0, stream>>>(xq, qhT);
  k_masksum<<<64, 256, 0, stream>>>(mask, n_cnt2);
  k_suml<<<dim3(16, 4), 256, 0, stream>>>(xq, sum_l);

  dim3 ga(S / 64, H, Bz);
  k_attn2<0><<<ga, 256, 0, stream>>>(xq, mask, nullptr, nullptr, nullptr, nullptr, denom);

  k_wwithin<<<Bz * H, 256, 0, stream>>>(sum_l, n_cnt2, denom, w_row);

  k_attn2<1><<<ga, 256, 0, stream>>>(xq, mask, qhT, w_row, attn, pvb, nullptr);

  k_gemm_bf<1, false, false><<<gg, 256, 0, stream>>>(pvb, Wo, bo, out, nullptr, nullptr);
}

// Round 5
// 256.881 us; speedup vs baseline: 2.8808x; 1.4957x over previous
//
#include <hip/hip_runtime.h>
#include <math.h>

// MultiHeadAttention_22067541967542 — round 5: bf16 end-to-end, conversion-free
// inner loops. B=4, S=1024, D=1024, H=16, dh=64. k/v/is_training dead.
// w_betw == 1/16 exactly (f32 absorption in reference, round-2 analysis).
// ws is large (~1.1 GB per fillBuffer evidence) -> no aliasing games.
// Pipeline:
//   k_prep: masksum (n_cnt2) + BN params + zero cs
//   k_bnq:  qbn = BN(q) bf16
//   k_wt:   WqT/WqqT/WoT bf16 [N][K] (transposed weights)
//   k_gemm2<relu,bf16>: x1b = relu(qbn@WqT+bq)
//   k_gemm2<-,bf16>:    xqb = x1b@WqqT+bqq          [d_out scratch, bf16]
//   k_cvt:  qhT bf16 [B,H,dh,S] + colsum atomics (cs)
//   k_suml2: sum_l[bh,q] = dot(xqb_head_row, cs)/8  (factorized logit row-sum)
//   k_attn2<0>: QK^T -> denom
//   k_wwithin:  f64 z-norm softmax -> w_row = w_within/16/denom
//   k_attn2<1>: recompute QK^T -> attn=p*w_row, PV -> pvb (bf16)
//   k_gemm2<-,f32>: out = pvb@WoT+bo
// LDS: 128B rows + XOR swizzle byte^=((row&7)<<4) everywhere (2-way = free).

constexpr int Bz = 4, S = 1024, D = 1024, H = 16, DH = 64;
constexpr int N_ROWS = Bz * S; // 4096
#define BN_EPS 1e-3f
#define NEG_BIG -1e9f

typedef __attribute__((ext_vector_type(8))) short bf16x8;
typedef __attribute__((ext_vector_type(8))) unsigned short u16x8;
typedef __attribute__((ext_vector_type(4))) unsigned short u16x4;
typedef __attribute__((ext_vector_type(4))) float f32x4;

__device__ inline unsigned short f2bf(float f) {
  union { float f; unsigned int u; } v; v.f = f;
  unsigned int u = v.u;
  return (unsigned short)((u + 0x7FFFu + ((u >> 16) & 1u)) >> 16); // RNE
}
__device__ inline float bf2f(unsigned short h) {
  union { unsigned int u; float f; } v; v.u = ((unsigned int)h) << 16;
  return v.f;
}
__device__ inline bf16x8 pack8(float4 a, float4 b) {
  bf16x8 v;
  v[0] = (short)f2bf(a.x); v[1] = (short)f2bf(a.y);
  v[2] = (short)f2bf(a.z); v[3] = (short)f2bf(a.w);
  v[4] = (short)f2bf(b.x); v[5] = (short)f2bf(b.y);
  v[6] = (short)f2bf(b.z); v[7] = (short)f2bf(b.w);
  return v;
}
__device__ inline float4 bnf(float4 f, float4 s, float4 sh) {
  return make_float4(fmaf(f.x, s.x, sh.x), fmaf(f.y, s.y, sh.y),
                     fmaf(f.z, s.z, sh.z), fmaf(f.w, s.w, sh.w));
}

// ---- prep: mask row-sums (blocks 0..63) + BN params + zero cs (blocks 64..67)
__global__ __launch_bounds__(256)
void k_prep(const int* __restrict__ mask, const float* __restrict__ gamma,
            const float* __restrict__ beta, const float* __restrict__ mean,
            const float* __restrict__ var, float* __restrict__ bnsc,
            float* __restrict__ bnsh, float* __restrict__ n_cnt2,
            float* __restrict__ cs) {
  const int bid = blockIdx.x, t = threadIdx.x;
  if (bid < 64) {
    const int row = bid * 64 + (t >> 2);
    const int4* mp = (const int4*)&mask[(size_t)row * 1024 + (t & 3) * 256];
    int s = 0;
#pragma unroll 8
    for (int i = 0; i < 64; ++i) { int4 m = mp[i]; s += (m.x + m.y) + (m.z + m.w); }
    s += __shfl_xor(s, 1, 64);
    s += __shfl_xor(s, 2, 64);
    if ((t & 3) == 0) n_cnt2[row] = (float)s;
  } else {
    const int i = (bid - 64) * 256 + t; // 0..1023
    float sc = gamma[i] * rsqrtf(var[i] + BN_EPS);
    bnsc[i] = sc;
    bnsh[i] = beta[i] - mean[i] * sc;
    *(float4*)&cs[i * 4] = make_float4(0.f, 0.f, 0.f, 0.f);
  }
}

// ---- qbn = BN(q) as bf16, elementwise (8 per thread)
__global__ __launch_bounds__(256)
void k_bnq(const float* __restrict__ q, const float* __restrict__ bnsc,
           const float* __restrict__ bnsh, unsigned short* __restrict__ qbn) {
  const size_t e0 = ((size_t)blockIdx.x * 256 + threadIdx.x) * 8;
  const int col = (int)(e0 & 1023);
  float4 f0 = *(const float4*)&q[e0], f1 = *(const float4*)&q[e0 + 4];
  float4 s0 = *(const float4*)&bnsc[col], s1 = *(const float4*)&bnsc[col + 4];
  float4 h0 = *(const float4*)&bnsh[col], h1 = *(const float4*)&bnsh[col + 4];
  *(bf16x8*)&qbn[e0] = pack8(bnf(f0, s0, h0), bnf(f1, s1, h1));
}

// ---- weight transpose: W f32 [K][N] -> T bf16 [N][K], 64x64 tiles, z picks weight
__global__ __launch_bounds__(256)
void k_wt(const float* __restrict__ W0, const float* __restrict__ W1,
          const float* __restrict__ W2, unsigned short* __restrict__ T0,
          unsigned short* __restrict__ T1, unsigned short* __restrict__ T2) {
  const float* W = blockIdx.z == 0 ? W0 : (blockIdx.z == 1 ? W1 : W2);
  unsigned short* T = blockIdx.z == 0 ? T0 : (blockIdx.z == 1 ? T1 : T2);
  __shared__ float Ls[64][65];
  const int t = threadIdx.x;
  const int k0 = blockIdx.x * 64, n0 = blockIdx.y * 64;
  {
    const int r = t >> 2, c0 = (t & 3) * 16;
#pragma unroll
    for (int i = 0; i < 4; ++i) {
      float4 f = *(const float4*)&W[(size_t)(k0 + r) * 1024 + n0 + c0 + 4 * i];
      Ls[r][c0 + 4 * i] = f.x; Ls[r][c0 + 4 * i + 1] = f.y;
      Ls[r][c0 + 4 * i + 2] = f.z; Ls[r][c0 + 4 * i + 3] = f.w;
    }
  }
  __syncthreads();
  {
    const int d = t >> 2, c = t & 3; // output row n0+d, k chunk c*16
    u16x8 o0, o1;
#pragma unroll
    for (int i = 0; i < 8; ++i) {
      o0[i] = f2bf(Ls[c * 16 + i][d]);
      o1[i] = f2bf(Ls[c * 16 + 8 + i][d]);
    }
    unsigned short* dst = &T[(size_t)(n0 + d) * 1024 + k0 + c * 16];
    *(u16x8*)dst = o0;
    *(u16x8*)(dst + 8) = o1;
  }
}

// ---- uniform bf16 GEMM: C[M=4096,N=1024] = A[M][K=1024] @ BT[N][K]^T + bias
// Tile 128x64, BK=64, 256 thr (4 waves 2x2 -> wave-tile 64x32).
template<bool RELU, bool OUTBF>
__global__ __launch_bounds__(256)
void k_gemm2(const unsigned short* __restrict__ A, const unsigned short* __restrict__ BT,
             const float* __restrict__ bias, void* __restrict__ C) {
  __shared__ unsigned short As[128 * 64]; // [m][k], 128B rows, swz ^((row&7)<<4)
  __shared__ unsigned short Bs[64 * 64];  // [n][k], 128B rows, swz
  const int t = threadIdx.x;
  const int w = t >> 6, l = t & 63, l15 = l & 15, l4 = l >> 4;
  const int m0 = blockIdx.x * 128, n0 = blockIdx.y * 64;
  const int wm = (w >> 1) * 64, wn = (w & 1) * 32;

  f32x4 acc[4][2];
#pragma unroll
  for (int i = 0; i < 4; ++i)
#pragma unroll
    for (int j = 0; j < 2; ++j) acc[i][j] = (f32x4){0.f, 0.f, 0.f, 0.f};

  for (int k0 = 0; k0 < 1024; k0 += 64) {
    __syncthreads();
    // stage A: 128 rows x 8 slots(16B) = 1024 chunks, 4 per thread
#pragma unroll
    for (int i = 0; i < 4; ++i) {
      const int c = i * 256 + t, row = c >> 3, slot = c & 7;
      bf16x8 v = *(const bf16x8*)&A[(size_t)(m0 + row) * 1024 + k0 + slot * 8];
      *(bf16x8*)((char*)As + row * 128 + ((slot * 16) ^ ((row & 7) << 4))) = v;
    }
    // stage B: 64 rows x 8 slots = 512 chunks, 2 per thread
#pragma unroll
    for (int i = 0; i < 2; ++i) {
      const int c = i * 256 + t, row = c >> 3, slot = c & 7;
      bf16x8 v = *(const bf16x8*)&BT[(size_t)(n0 + row) * 1024 + k0 + slot * 8];
      *(bf16x8*)((char*)Bs + row * 128 + ((slot * 16) ^ ((row & 7) << 4))) = v;
    }
    __syncthreads();
    bf16x8 af[4][2], bfr[2][2];
#pragma unroll
    for (int bm = 0; bm < 4; ++bm) {
      const int r = wm + bm * 16 + l15;
#pragma unroll
      for (int kk = 0; kk < 2; ++kk)
        af[bm][kk] = *(const bf16x8*)((const char*)As + r * 128 +
                                      ((kk * 64 + l4 * 16) ^ ((r & 7) << 4)));
    }
#pragma unroll
    for (int bn = 0; bn < 2; ++bn) {
      const int r = wn + bn * 16 + l15;
#pragma unroll
      for (int kk = 0; kk < 2; ++kk)
        bfr[bn][kk] = *(const bf16x8*)((const char*)Bs + r * 128 +
                                       ((kk * 64 + l4 * 16) ^ ((r & 7) << 4)));
    }
#pragma unroll
    for (int bm = 0; bm < 4; ++bm)
#pragma unroll
      for (int bn = 0; bn < 2; ++bn) {
        acc[bm][bn] = __builtin_amdgcn_mfma_f32_16x16x32_bf16(af[bm][0], bfr[bn][0], acc[bm][bn], 0, 0, 0);
        acc[bm][bn] = __builtin_amdgcn_mfma_f32_16x16x32_bf16(af[bm][1], bfr[bn][1], acc[bm][bn], 0, 0, 0);
      }
  }
  float bv[2];
#pragma unroll
  for (int bn = 0; bn < 2; ++bn) bv[bn] = bias[n0 + wn + bn * 16 + l15];
#pragma unroll
  for (int bm = 0; bm < 4; ++bm)
#pragma unroll
    for (int bn = 0; bn < 2; ++bn)
#pragma unroll
      for (int r = 0; r < 4; ++r) {
        float v = acc[bm][bn][r] + bv[bn];
        if (RELU) v = fmaxf(v, 0.f);
        const size_t idx = (size_t)(m0 + wm + bm * 16 + l4 * 4 + r) * 1024 +
                           n0 + wn + bn * 16 + l15;
        if (OUTBF) ((unsigned short*)C)[idx] = f2bf(v);
        else ((float*)C)[idx] = v;
      }
}

// ---- xqb bf16 [4096][1024] -> qhT bf16 [B,H,dh,S]; fused colsum atomics
__global__ __launch_bounds__(256)
void k_cvt(const unsigned short* __restrict__ xqb, unsigned short* __restrict__ qhT,
           float* __restrict__ cs) {
  __shared__ unsigned short Ls[64][72];
  const int t = threadIdx.x;
  const int b = blockIdx.x >> 4;
  const int sb = (blockIdx.x & 15) * 64;
  const int h = blockIdx.y;
  {
    const int r = t >> 2, c0 = (t & 3) * 16;
    const unsigned short* src = &xqb[(size_t)(b * 1024 + sb + r) * 1024 + h * 64 + c0];
    u16x8 a = *(const u16x8*)src;
    u16x8 b8 = *(const u16x8*)(src + 8);
    *(u16x8*)&Ls[r][c0] = a;
    *(u16x8*)&Ls[r][c0 + 8] = b8;
  }
  __syncthreads();
  {
    const int d = t >> 2, c = t & 3;
    u16x8 o0, o1;
#pragma unroll
    for (int i = 0; i < 8; ++i) {
      o0[i] = Ls[c * 16 + i][d];
      o1[i] = Ls[c * 16 + 8 + i][d];
    }
    unsigned short* dst = &qhT[(size_t)((b * 16 + h) * 64 + d) * 1024 + sb + c * 16];
    *(u16x8*)dst = o0;
    *(u16x8*)(dst + 8) = o1;
  }
  if (t < 64) {
    float s = 0.f;
#pragma unroll 8
    for (int i = 0; i < 64; ++i) s += bf2f(Ls[i][t]);
    atomicAdd(&cs[b * 1024 + h * 64 + t], s);
  }
}

// ---- sum_l[bh,q] = dot(xqb_head_row[q], cs[b,h*64..]) / 8
__global__ __launch_bounds__(256)
void k_suml2(const unsigned short* __restrict__ xqb, const float* __restrict__ cs,
             float* __restrict__ sum_l) {
  const int qc = blockIdx.x, b = blockIdx.y;
  const int t = threadIdx.x;
  const int h = t >> 4, dg = t & 15;
  const float4 c4 = *(const float4*)&cs[b * 1024 + t * 4];
  for (int qi = 0; qi < 64; ++qi) {
    const int q = qc * 64 + qi;
    u16x4 xv = *(const u16x4*)&xqb[(size_t)(b * 1024 + q) * 1024 + t * 4];
    float s = bf2f(xv[0]) * c4.x + bf2f(xv[1]) * c4.y +
              bf2f(xv[2]) * c4.z + bf2f(xv[3]) * c4.w;
    s += __shfl_xor(s, 1, 64);
    s += __shfl_xor(s, 2, 64);
    s += __shfl_xor(s, 4, 64);
    s += __shfl_xor(s, 8, 64);
    if (dg == 0) sum_l[(size_t)(b * 16 + h) * 1024 + q] = s * 0.125f;
  }
}

// ---- attention: PASS 0 denom; PASS 1 attn=p*w_row + pvb. Source xqb bf16.
template<int PASS>
__global__ __launch_bounds__(256)
void k_attn2(const unsigned short* __restrict__ xqb, const int* __restrict__ mask,
             const unsigned short* __restrict__ qhT, const float* __restrict__ w_row,
             float* __restrict__ attn, unsigned short* __restrict__ pvb,
             float* __restrict__ denom) {
  __shared__ unsigned short Ks[64 * 64]; // [key][dh], 128B rows, swz ^((row&7)<<4)
  __shared__ unsigned short Pst[PASS ? 4 * 16 * 64 : 8]; // per-wave [q][key]

  const int t = threadIdx.x;
  const int w = t >> 6, l = t & 63;
  const int l15 = l & 15, l4 = l >> 4;
  const int q0 = blockIdx.x * 64;
  const int h = blockIdx.y, b = blockIdx.z;
  const int bh = b * 16 + h;

  // Q fragments: direct bf16 loads
  bf16x8 qa0, qa1;
  {
    const unsigned short* qp =
        &xqb[(size_t)(b * 1024 + q0 + w * 16 + l15) * 1024 + h * 64 + l4 * 8];
    qa0 = *(const bf16x8*)qp;
    qa1 = *(const bf16x8*)(qp + 32);
  }

  float wsc[4];
  if (PASS == 1) {
#pragma unroll
    for (int r = 0; r < 4; ++r)
      wsc[r] = w_row[(size_t)bh * 1024 + q0 + w * 16 + l4 * 4 + r];
  }

  float dsum[4] = {0.f, 0.f, 0.f, 0.f};
  f32x4 vacc[4];
#pragma unroll
  for (int c = 0; c < 4; ++c) vacc[c] = (f32x4){0.f, 0.f, 0.f, 0.f};

  for (int k0 = 0; k0 < 1024; k0 += 64) {
    __syncthreads();
    // cooperative K-tile stage: pure bf16 copy, swizzled (2 x 16B per thread)
#pragma unroll
    for (int i = 0; i < 2; ++i) {
      const int c = i * 256 + t, row = c >> 3, slot = c & 7;
      bf16x8 v = *(const bf16x8*)&xqb[(size_t)(b * 1024 + k0 + row) * 1024 + h * 64 + slot * 8];
      *(bf16x8*)((char*)Ks + row * 128 + ((slot * 16) ^ ((row & 7) << 4))) = v;
    }
    __syncthreads();

    // QK^T: 4 col-tiles x (dh=64 in 2 mfmas)
    f32x4 lacc[4];
#pragma unroll
    for (int c = 0; c < 4; ++c) {
      const int r = c * 16 + l15;
      const char* kb = (const char*)Ks + r * 128;
      const int rsw = (r & 7) << 4;
      bf16x8 kb0 = *(const bf16x8*)(kb + ((l4 * 16) ^ rsw));
      bf16x8 kb1 = *(const bf16x8*)(kb + ((64 + l4 * 16) ^ rsw));
      f32x4 z = (f32x4){0.f, 0.f, 0.f, 0.f};
      z = __builtin_amdgcn_mfma_f32_16x16x32_bf16(qa0, kb0, z, 0, 0, 0);
      z = __builtin_amdgcn_mfma_f32_16x16x32_bf16(qa1, kb1, z, 0, 0, 0);
      lacc[c] = z;
    }

    int mrr[4][4];
#pragma unroll
    for (int c = 0; c < 4; ++c)
#pragma unroll
      for (int r = 0; r < 4; ++r)
        mrr[c][r] = mask[(size_t)(b * 1024 + q0 + w * 16 + l4 * 4 + r) * 1024 +
                         k0 + c * 16 + l15];

#pragma unroll
    for (int c = 0; c < 4; ++c) {
#pragma unroll
      for (int r = 0; r < 4; ++r) {
        float p = __expf(fmaf((float)mrr[c][r], NEG_BIG, lacc[c][r] * 0.125f));
        if (PASS == 0) {
          dsum[r] += p;
        } else {
          attn[(size_t)(bh * 1024 + q0 + w * 16 + l4 * 4 + r) * 1024 +
               k0 + c * 16 + l15] = p * wsc[r];
          const int qq = l4 * 4 + r;
          *(unsigned short*)((char*)&Pst[w * 1024] + qq * 128 +
                             (((c * 16 + l15) * 2) ^ ((qq & 7) << 4))) = f2bf(p);
        }
      }
    }

    if (PASS == 1) {
      // PV: A = Pst row l15 (wave-private), B = qhT (L2-resident)
#pragma unroll
      for (int kk = 0; kk < 2; ++kk) {
        const char* pb = (const char*)&Pst[w * 1024] + l15 * 128;
        bf16x8 pa = *(const bf16x8*)(pb + ((kk * 64 + l4 * 16) ^ ((l15 & 7) << 4)));
#pragma unroll
        for (int c = 0; c < 4; ++c) {
          bf16x8 vb = *(const bf16x8*)&qhT[(size_t)(bh * 64 + c * 16 + l15) * 1024 +
                                           k0 + kk * 32 + l4 * 8];
          vacc[c] = __builtin_amdgcn_mfma_f32_16x16x32_bf16(pa, vb, vacc[c], 0, 0, 0);
        }
      }
    }
  }

  if (PASS == 0) {
#pragma unroll
    for (int r = 0; r < 4; ++r) {
      float d2 = dsum[r];
#pragma unroll
      for (int m = 1; m < 16; m <<= 1) d2 += __shfl_xor(d2, m, 64);
      if (l15 == 0)
        denom[(size_t)bh * 1024 + q0 + w * 16 + l4 * 4 + r] = d2;
    }
  } else {
#pragma unroll
    for (int c = 0; c < 4; ++c)
#pragma unroll
      for (int r = 0; r < 4; ++r)
        pvb[(size_t)(b * 1024 + q0 + w * 16 + l4 * 4 + r) * 1024 +
            h * 64 + c * 16 + l15] = f2bf(vacc[c][r] * wsc[r]);
  }
}

// ---- per (b,h): w_within (f64) -> w_row = w_within * (1/16) / denom
__global__ __launch_bounds__(256)
void k_wwithin(const float* __restrict__ sum_l, const float* __restrict__ n_cnt2,
               const float* __restrict__ denom, float* __restrict__ w_row) {
  __shared__ double buf[1024];
  __shared__ double red[256];
  __shared__ double sh_mu, sh_sd, sh_zm, sh_es;
  const int bh = blockIdx.x, t = threadIdx.x;
  const int base = bh << 10;
  const int nbase = (bh >> 4) << 10;
  double part = 0;
  for (int q2 = t; q2 < 1024; q2 += 256) {
    double last = ((double)sum_l[base + q2] - 1e9 * (double)n_cnt2[nbase + q2]) * (1.0 / 1024.0);
    buf[q2] = last; part += last;
  }
  red[t] = part; __syncthreads();
  for (int s2 = 128; s2 > 0; s2 >>= 1) { if (t < s2) red[t] += red[t + s2]; __syncthreads(); }
  if (t == 0) sh_mu = red[0] * (1.0 / 1024.0);
  __syncthreads();
  const double mu = sh_mu;
  part = 0;
  for (int q2 = t; q2 < 1024; q2 += 256) { double d = buf[q2] - mu; part += d * d; }
  red[t] = part; __syncthreads();
  for (int s2 = 128; s2 > 0; s2 >>= 1) { if (t < s2) red[t] += red[t + s2]; __syncthreads(); }
  if (t == 0) sh_sd = sqrt(red[0] * (1.0 / 1024.0));
  __syncthreads();
  const double dn = sh_sd * 2.0 + 1e-10;
  part = -1e300;
  for (int q2 = t; q2 < 1024; q2 += 256) {
    double z = (buf[q2] - mu) / dn;
    buf[q2] = z;
    part = fmax(part, z);
  }
  red[t] = part; __syncthreads();
  for (int s2 = 128; s2 > 0; s2 >>= 1) { if (t < s2) red[t] = fmax(red[t], red[t + s2]); __syncthreads(); }
  if (t == 0) sh_zm = red[0];
  __syncthreads();
  const double zm = sh_zm;
  part = 0;
  for (int q2 = t; q2 < 1024; q2 += 256) {
    double e = exp(buf[q2] - zm);
    buf[q2] = e; part += e;
  }
  red[t] = part; __syncthreads();
  for (int s2 = 128; s2 > 0; s2 >>= 1) { if (t < s2) red[t] += red[t + s2]; __syncthreads(); }
  if (t == 0) sh_es = red[0];
  __syncthreads();
  const double tot = sh_es;
  for (int q2 = t; q2 < 1024; q2 += 256) {
    w_row[base + q2] = (float)(buf[q2] / tot * 0.0625 / (double)denom[base + q2]);
  }
}

extern "C" void kernel_launch(void* const* d_in, const int* in_sizes, int n_in,
                              void* d_out, int out_size, void* d_ws, size_t ws_size,
                              hipStream_t stream) {
  const float* q      = (const float*)d_in[0];
  const int*   mask   = (const int*)d_in[3];
  const float* q_gamma = (const float*)d_in[5];
  const float* q_beta  = (const float*)d_in[6];
  const float* q_mean  = (const float*)d_in[7];
  const float* q_var   = (const float*)d_in[8];
  const float* Wq  = (const float*)d_in[9];
  const float* bq  = (const float*)d_in[10];
  const float* Wqq = (const float*)d_in[11];
  const float* bqq = (const float*)d_in[12];
  const float* Wo  = (const float*)d_in[13];
  const float* bo  = (const float*)d_in[14];

  float* out  = (float*)d_out;                          // [4096,1024]
  float* attn = (float*)d_out + (size_t)N_ROWS * D;     // [B,H,S,S]
  unsigned short* xqb = (unsigned short*)d_out;         // bf16 scratch in out region

  char* ws = (char*)d_ws; // ws is large (~1.1 GB poison observed); flat layout
  unsigned short* x1b = (unsigned short*)(ws);                  // 8 MB
  unsigned short* qhT = (unsigned short*)(ws + (8u << 20));     // 8 MB
  unsigned short* pvb = (unsigned short*)(ws + (16u << 20));    // 8 MB
  unsigned short* qbn = (unsigned short*)(ws + (24u << 20));    // 8 MB
  unsigned short* WqT  = (unsigned short*)(ws + (32u << 20));   // 2 MB
  unsigned short* WqqT = (unsigned short*)(ws + (34u << 20));   // 2 MB
  unsigned short* WoT  = (unsigned short*)(ws + (36u << 20));   // 2 MB
  float* bnsc   = (float*)(ws + (38u << 20));
  float* bnsh   = bnsc + 1024;
  float* cs     = bnsh + 1024;      // 4096
  float* sum_l  = cs + 4096;        // 65536
  float* denom  = sum_l + 65536;
  float* w_row  = denom + 65536;
  float* n_cnt2 = w_row + 65536;    // 4096

  k_prep<<<68, 256, 0, stream>>>(mask, q_gamma, q_beta, q_mean, q_var,
                                 bnsc, bnsh, n_cnt2, cs);
  k_bnq<<<2048, 256, 0, stream>>>(q, bnsc, bnsh, qbn);
  k_wt<<<dim3(16, 16, 3), 256, 0, stream>>>(Wq, Wqq, Wo, WqT, WqqT, WoT);

  dim3 gg(32, 16);
  k_gemm2<true, true><<<gg, 256, 0, stream>>>(qbn, WqT, bq, x1b);
  k_gemm2<false, true><<<gg, 256, 0, stream>>>(x1b, WqqT, bqq, xqb);

  k_cvt<<<dim3(64, 16), 256, 0, stream>>>(xqb, qhT, cs);
  k_suml2<<<dim3(16, 4), 256, 0, stream>>>(xqb, cs, sum_l);

  dim3 ga(S / 64, H, Bz);
  k_attn2<0><<<ga, 256, 0, stream>>>(xqb, mask, nullptr, nullptr, nullptr, nullptr, denom);
  k_wwithin<<<Bz * H, 256, 0, stream>>>(sum_l, n_cnt2, denom, w_row);
  k_attn2<1><<<ga, 256, 0, stream>>>(xqb, mask, qhT, w_row, attn, pvb, nullptr);

  k_gemm2<false, false><<<gg, 256, 0, stream>>>(pvb, WoT, bo, out);
}